// Round 2
// baseline (265.874 us; speedup 1.0000x reference)
//
#include <hip/hip_runtime.h>

constexpr int K_CODES = 512;
constexpr int D_DIM   = 64;
constexpr int HW      = 4096;               // 64*64
constexpr int BATCH   = 32;
constexpr int N_ROWS  = BATCH * HW;         // 131072

// One thread per spatial vector. Bit-exact emulation of the f32 reference:
//   dists[n,k] = fl( fl(zz_n - fl(2*dot_nk)) + ee_k )
//   zz_n  : sequential d=0..63, separate mul/add rounding (XLA-CPU reduce)
//   dot_nk: sequential d=0..63 fma chain (Eigen/oneDNN sgemm accumulation)
//   ee_k  : sequential d=0..63, separate mul/add rounding
//   argmin: ascending k, strict < (first occurrence of min, like np.argmin)
__global__ __launch_bounds__(256) void vq_nearest(const float* __restrict__ zin,
                                                  const float* __restrict__ emb,
                                                  float* __restrict__ out) {
#pragma clang fp contract(off)
    __shared__ float s_ee[K_CODES];
    const int tid = threadIdx.x;

    // ee[k] = |e_k|^2, sequential, separate rounding; 2 codes per thread
    for (int k = tid; k < K_CODES; k += 256) {
        const float* w = emb + k * D_DIM;
        float acc = 0.f;
        for (int d = 0; d < D_DIM; ++d) { float q = w[d] * w[d]; acc = acc + q; }
        s_ee[k] = acc;
    }
    __syncthreads();

    const int n = blockIdx.x * 256 + tid;
    const int b = n >> 12;                  // batch
    const int p = n & (HW - 1);             // h*64+w
    const float* zp = zin + (size_t)b * (D_DIM * HW) + p;

    // z row into registers (coalesced across lanes for each d)
    float zr[D_DIM];
#pragma unroll
    for (int d = 0; d < D_DIM; ++d) zr[d] = zp[(size_t)d * HW];

    // zz: strict sequential sum of squares, no fma contraction
    float zz = 0.f;
#pragma unroll
    for (int d = 0; d < D_DIM; ++d) { float q = zr[d] * zr[d]; zz = zz + q; }

    float best = 3.4e38f;
    int bi = 0;

    // 8 codes in flight (independent sequential fma chains -> ILP hides latency)
    for (int k0 = 0; k0 < K_CODES; k0 += 8) {
        const float* w = emb + (size_t)k0 * D_DIM;   // wave-uniform -> s_load path
        float dot[8];
#pragma unroll
        for (int j = 0; j < 8; ++j) dot[j] = 0.f;
#pragma unroll
        for (int d = 0; d < D_DIM; ++d) {
            const float z = zr[d];
#pragma unroll
            for (int j = 0; j < 8; ++j)
                dot[j] = __builtin_fmaf(w[j * D_DIM + d], z, dot[j]);
        }
#pragma unroll
        for (int j = 0; j < 8; ++j) {
            const float m    = 2.0f * dot[j];        // exact (x2)
            const float s    = zz - m;               // one rounding
            const float dist = s + s_ee[k0 + j];     // one rounding
            if (dist < best) { best = dist; bi = k0 + j; }
        }
    }

    // gather chosen code, write both outputs (z_q_x and z_q_x_bar identical)
    const float* wb = emb + (size_t)bi * D_DIM;
    float* o1 = out + (size_t)b * (D_DIM * HW) + p;
    float* o2 = o1 + (size_t)BATCH * D_DIM * HW;
#pragma unroll
    for (int d = 0; d < D_DIM; ++d) {
        const float v = wb[d];
        o1[(size_t)d * HW] = v;
        o2[(size_t)d * HW] = v;
    }
}

extern "C" void kernel_launch(void* const* d_in, const int* in_sizes, int n_in,
                              void* d_out, int out_size, void* d_ws, size_t ws_size,
                              hipStream_t stream) {
    const float* z   = (const float*)d_in[0];
    const float* emb = (const float*)d_in[1];
    float* out = (float*)d_out;
    hipLaunchKernelGGL(vq_nearest, dim3(N_ROWS / 256), dim3(256), 0, stream,
                       z, emb, out);
}